// Round 11
// baseline (273.267 us; speedup 1.0000x reference)
//
#include <hip/hip_runtime.h>

#pragma clang fp contract(off)

#define BATCH 16
#define NPTS  4096
#define KNN   32
#define CH    30

// Kernel A (bound): 8 waves, chunk 512, top-4 per chunk (union 8*4=32 -> bound)
#define NWA     8
#define CHUNKA  (NPTS / NWA)     // 512
// Kernel B (collect+select): 4 waves, chunk 1024, FIFO of d<=t_cap survivors
#define NWB     4
#define CHUNKB  (NPTS / NWB)     // 1024
#define FD      48               // per-(region,lane) FIFO depth; slot FD = trash
#define FSTRIDE 50               // u16 slots per lane column (>= FD+1)

#define INF_F __builtin_inff()

__device__ __forceinline__ unsigned enc_f32(float f) {
    unsigned u = __float_as_uint(f);
    return (u & 0x80000000u) ? ~u : (u | 0x80000000u);
}
__device__ __forceinline__ float dec_f32(unsigned e) {
    unsigned u = (e & 0x80000000u) ? (e & 0x7FFFFFFFu) : ~e;
    return __uint_as_float(u);
}

__device__ __forceinline__ float med3f(float a, float b, float c) {
#if __has_builtin(__builtin_amdgcn_fmed3f)
    return __builtin_amdgcn_fmed3f(a, b, c);
#else
    float r;
    asm("v_med3_f32 %0, %1, %2, %3" : "=v"(r) : "v"(a), "v"(b), "v"(c));
    return r;
#endif
}

// Difference-form squared distance, fma-fixed: ONE formula in EVERY pass of
// BOTH kernels -> bit-identical d everywhere (contract off).
__device__ __forceinline__ float dist3d(float qx, float qy, float qz,
                                        float px, float py, float pz) {
    float r0 = px - qx, r1 = py - qy, r2 = pz - qz;
    return __builtin_fmaf(r0, r0, __builtin_fmaf(r1, r1, r2 * r2));
}

__global__ void init_pool_kernel(unsigned* __restrict__ pool) {
    int i = blockIdx.x * blockDim.x + threadIdx.x;
    if (i < BATCH * CH) pool[i] = 0u;   // 0 is below every encoded finite float
}

// ---- Kernel A: per-query upper bound t_cap on the 32nd-smallest distance.
// Named-scalar top-4 (no arrays -> no scratch risk).
__launch_bounds__(512, 8)
__global__ void knn_bound_kernel(const float* __restrict__ x,
                                 float* __restrict__ tcap) {
    __shared__ float t8[NWA * 64];                 // 2 KB

    const int b   = blockIdx.x >> 6;
    const int qg  = blockIdx.x & 63;
    const int tid = threadIdx.x;
    const int w   = tid >> 6;                      // wave id = chunk id (0..7)
    const int l   = tid & 63;
    const int q   = qg * 64 + l;
    const float* __restrict__ xb = x + (size_t)b * NPTS * 3;

    const float qx = xb[q * 3 + 0], qy = xb[q * 3 + 1], qz = xb[q * 3 + 2];
    const float4* __restrict__ g4 = (const float4*)xb + (size_t)w * (CHUNKA * 3 / 4);

    float B0 = INF_F, B1 = INF_F, B2 = INF_F, B3 = INF_F;

#define INSERT4(dv)                          \
    {                                        \
        B3 = med3f(B2, B3, (dv));            \
        B2 = med3f(B1, B2, (dv));            \
        B1 = med3f(B0, B1, (dv));            \
        B0 = fminf(B0, (dv));                \
    }

#pragma unroll 2
    for (int m4 = 0; m4 < CHUNKA / 4; ++m4) {
        float4 A = g4[3 * m4], B = g4[3 * m4 + 1], C = g4[3 * m4 + 2];
        float d0 = dist3d(qx, qy, qz, A.x, A.y, A.z);
        float d1 = dist3d(qx, qy, qz, A.w, B.x, B.y);
        float d2 = dist3d(qx, qy, qz, B.z, B.w, C.x);
        float d3 = dist3d(qx, qy, qz, C.y, C.z, C.w);
        INSERT4(d0); INSERT4(d1); INSERT4(d2); INSERT4(d3);
    }
#undef INSERT4

    t8[w * 64 + l] = B3;
    __syncthreads();

    if (w == 0) {
        float t = t8[l];
#pragma unroll
        for (int ww = 1; ww < NWA; ++ww) t = fmaxf(t, t8[ww * 64 + l]);
        tcap[(size_t)b * NPTS + q] = t;
    }
}

// ---- Kernel B: collect survivors (d <= t_cap) then exact top-32 + stats.
// ZERO local arrays anywhere -> everything in VGPRs.
__launch_bounds__(256, 4)
__global__ void knn_feat_kernel(const float* __restrict__ x,
                                const float* __restrict__ tcap,
                                unsigned* __restrict__ pool) {
    __shared__ unsigned short fifo[NWB * 64 * FSTRIDE];    // 25.0 KB [w][l][slot]
    __shared__ unsigned char  cbs[NWB * 64];               // 256 B

    const int b   = blockIdx.x >> 6;
    const int qg  = blockIdx.x & 63;
    const int tid = threadIdx.x;
    const int w   = tid >> 6;                      // wave id = chunk id (0..3)
    const int l   = tid & 63;
    const int q   = qg * 64 + l;
    const float* __restrict__ xb = x + (size_t)b * NPTS * 3;

    const float qx = xb[q * 3 + 0], qy = xb[q * 3 + 1], qz = xb[q * 3 + 2];
    const float t_cap = tcap[(size_t)b * NPTS + q];

    const float4* __restrict__ g4 = (const float4*)xb + (size_t)w * (CHUNKB * 3 / 4);

    // Pass 2: branchless collect of GLOBAL u16 indices with d <= t_cap.
    unsigned short* __restrict__ fl = fifo + (w * 64 + l) * FSTRIDE;
    int cnt = 0;
#pragma unroll 2
    for (int m4 = 0; m4 < CHUNKB / 4; ++m4) {
        float4 A = g4[3 * m4], B = g4[3 * m4 + 1], C = g4[3 * m4 + 2];
        float d0 = dist3d(qx, qy, qz, A.x, A.y, A.z);
        float d1 = dist3d(qx, qy, qz, A.w, B.x, B.y);
        float d2 = dist3d(qx, qy, qz, B.z, B.w, C.x);
        float d3 = dist3d(qx, qy, qz, C.y, C.z, C.w);
        int mb = w * CHUNKB + m4 * 4;              // global candidate index
        { bool t = (d0 <= t_cap) && (cnt < FD); fl[t ? cnt : FD] = (unsigned short)(mb + 0); cnt += t; }
        { bool t = (d1 <= t_cap) && (cnt < FD); fl[t ? cnt : FD] = (unsigned short)(mb + 1); cnt += t; }
        { bool t = (d2 <= t_cap) && (cnt < FD); fl[t ? cnt : FD] = (unsigned short)(mb + 2); cnt += t; }
        { bool t = (d3 <= t_cap) && (cnt < FD); fl[t ? cnt : FD] = (unsigned short)(mb + 3); cnt += t; }
    }
    cbs[w * 64 + l] = (unsigned char)cnt;
    __syncthreads();

    if (w != 0) return;   // no barriers past this point

    // ---- Phase 3 (wave 0): named-scalar top-32 + stats, pipelined loads. ----
    int cc0 = cbs[0 * 64 + l], cc1 = cbs[1 * 64 + l],
        cc2 = cbs[2 * 64 + l], cc3 = cbs[3 * 64 + l];

#define WMAX(v_)                                          \
    {                                                     \
        _Pragma("unroll")                                 \
        for (int off = 32; off >= 1; off >>= 1) {         \
            int o_ = __shfl_xor((v_), off, 64);           \
            (v_) = (o_ > (v_)) ? o_ : (v_);               \
        }                                                 \
    }
    int mc0 = cc0; WMAX(mc0);
    int mc1 = cc1; WMAX(mc1);
    int mc2 = cc2; WMAX(mc2);
    int mc3 = cc3; WMAX(mc3);
#undef WMAX

    // Named top-32 list (ascending). Descending insert reads old neighbors.
    float A00 = INF_F, A01 = INF_F, A02 = INF_F, A03 = INF_F,
          A04 = INF_F, A05 = INF_F, A06 = INF_F, A07 = INF_F,
          A08 = INF_F, A09 = INF_F, A10 = INF_F, A11 = INF_F,
          A12 = INF_F, A13 = INF_F, A14 = INF_F, A15 = INF_F,
          A16 = INF_F, A17 = INF_F, A18 = INF_F, A19 = INF_F,
          A20 = INF_F, A21 = INF_F, A22 = INF_F, A23 = INF_F,
          A24 = INF_F, A25 = INF_F, A26 = INF_F, A27 = INF_F,
          A28 = INF_F, A29 = INF_F, A30 = INF_F, A31 = INF_F;

#define INS32(D)                                                              \
    {                                                                         \
        A31 = med3f(A30, A31, (D)); A30 = med3f(A29, A30, (D));               \
        A29 = med3f(A28, A29, (D)); A28 = med3f(A27, A28, (D));               \
        A27 = med3f(A26, A27, (D)); A26 = med3f(A25, A26, (D));               \
        A25 = med3f(A24, A25, (D)); A24 = med3f(A23, A24, (D));               \
        A23 = med3f(A22, A23, (D)); A22 = med3f(A21, A22, (D));               \
        A21 = med3f(A20, A21, (D)); A20 = med3f(A19, A20, (D));               \
        A19 = med3f(A18, A19, (D)); A18 = med3f(A17, A18, (D));               \
        A17 = med3f(A16, A17, (D)); A16 = med3f(A15, A16, (D));               \
        A15 = med3f(A14, A15, (D)); A14 = med3f(A13, A14, (D));               \
        A13 = med3f(A12, A13, (D)); A12 = med3f(A11, A12, (D));               \
        A11 = med3f(A10, A11, (D)); A10 = med3f(A09, A10, (D));               \
        A09 = med3f(A08, A09, (D)); A08 = med3f(A07, A08, (D));               \
        A07 = med3f(A06, A07, (D)); A06 = med3f(A05, A06, (D));               \
        A05 = med3f(A04, A05, (D)); A04 = med3f(A03, A04, (D));               \
        A03 = med3f(A02, A03, (D)); A02 = med3f(A01, A02, (D));               \
        A01 = med3f(A00, A01, (D)); A00 = fminf(A00, (D));                    \
    }

    // Load 4 survivor coords for group g_ (garbage slots masked in-bounds).
#define LOADG(flp, g_, X0, Y0, Z0, X1, Y1, Z1, X2, Y2, Z2, X3, Y3, Z3)        \
    {                                                                         \
        const unsigned* p32_ = (const unsigned*)((flp) + (g_) * 4);           \
        unsigned v0_ = p32_[0], v1_ = p32_[1];                                \
        int i0_ = (int)(v0_ & 0xFFFu);                                        \
        int i1_ = (int)((v0_ >> 16) & 0xFFFu);                                \
        int i2_ = (int)(v1_ & 0xFFFu);                                        \
        int i3_ = (int)((v1_ >> 16) & 0xFFFu);                                \
        const float* p0_ = xb + 3 * i0_;                                      \
        const float* p1_ = xb + 3 * i1_;                                      \
        const float* p2_ = xb + 3 * i2_;                                      \
        const float* p3_ = xb + 3 * i3_;                                      \
        X0 = p0_[0]; Y0 = p0_[1]; Z0 = p0_[2];                                \
        X1 = p1_[0]; Y1 = p1_[1]; Z1 = p1_[2];                                \
        X2 = p2_[0]; Y2 = p2_[1]; Z2 = p2_[2];                                \
        X3 = p3_[0]; Y3 = p3_[1]; Z3 = p3_[2];                                \
    }

#define REGION_SELECT(WW, CCW, MCW)                                           \
    {                                                                         \
        const unsigned short* flp = fifo + ((WW) * 64 + l) * FSTRIDE;         \
        const int c = (CCW);                                                  \
        const int grp = ((MCW) + 3) >> 2;                                     \
        if (grp > 0) {                                                        \
            float cx0, cy0, cz0, cx1, cy1, cz1, cx2, cy2, cz2, cx3, cy3, cz3; \
            LOADG(flp, 0, cx0, cy0, cz0, cx1, cy1, cz1, cx2, cy2, cz2, cx3, cy3, cz3); \
            for (int g = 0; g < grp; ++g) {                                   \
                float nx0, ny0, nz0, nx1, ny1, nz1, nx2, ny2, nz2, nx3, ny3, nz3; \
                int gn = (g + 1 < grp) ? (g + 1) : g;                         \
                LOADG(flp, gn, nx0, ny0, nz0, nx1, ny1, nz1, nx2, ny2, nz2, nx3, ny3, nz3); \
                float d0 = dist3d(qx, qy, qz, cx0, cy0, cz0);                 \
                float d1 = dist3d(qx, qy, qz, cx1, cy1, cz1);                 \
                float d2 = dist3d(qx, qy, qz, cx2, cy2, cz2);                 \
                float d3 = dist3d(qx, qy, qz, cx3, cy3, cz3);                 \
                int gi = g * 4;                                               \
                d0 = (gi + 0 < c) ? d0 : INF_F;                               \
                d1 = (gi + 1 < c) ? d1 : INF_F;                               \
                d2 = (gi + 2 < c) ? d2 : INF_F;                               \
                d3 = (gi + 3 < c) ? d3 : INF_F;                               \
                INS32(d0); INS32(d1); INS32(d2); INS32(d3);                   \
                cx0 = nx0; cy0 = ny0; cz0 = nz0;  cx1 = nx1; cy1 = ny1; cz1 = nz1; \
                cx2 = nx2; cy2 = ny2; cz2 = nz2;  cx3 = nx3; cy3 = ny3; cz3 = nz3; \
            }                                                                 \
        }                                                                     \
    }

    REGION_SELECT(0, cc0, mc0);
    REGION_SELECT(1, cc1, mc1);
    REGION_SELECT(2, cc2, mc2);
    REGION_SELECT(3, cc3, mc3);
#undef REGION_SELECT
#undef INS32

    const float thr = A31;
    int c_lt = (A00 < thr) + (A01 < thr) + (A02 < thr) + (A03 < thr)
             + (A04 < thr) + (A05 < thr) + (A06 < thr) + (A07 < thr)
             + (A08 < thr) + (A09 < thr) + (A10 < thr) + (A11 < thr)
             + (A12 < thr) + (A13 < thr) + (A14 < thr) + (A15 < thr)
             + (A16 < thr) + (A17 < thr) + (A18 < thr) + (A19 < thr)
             + (A20 < thr) + (A21 < thr) + (A22 < thr) + (A23 < thr)
             + (A24 < thr) + (A25 < thr) + (A26 < thr) + (A27 < thr)
             + (A28 < thr) + (A29 < thr) + (A30 < thr) + (A31 < thr);
    const int need = KNN - c_lt;                   // ties to take, in index order

    // ---- Stats pass over the same survivors (same pipeline). ----
    float s0 = 0.f, s1 = 0.f, s2 = 0.f;
    float ss0 = 0.f, ss1 = 0.f, ss2 = 0.f;
    float mx0 = -INF_F, mx1 = -INF_F, mx2 = -INF_F;
    float mn0 =  INF_F, mn1 =  INF_F, mn2 =  INF_F;
    int eq_seen = 0;

#define STAT1(PX, PY, PZ, ACT)                                                \
    {                                                                         \
        float d_ = dist3d(qx, qy, qz, (PX), (PY), (PZ));                      \
        d_ = (ACT) ? d_ : INF_F;                                              \
        bool is_eq_ = (d_ == thr);                                            \
        bool take_ = (d_ < thr) || (is_eq_ && eq_seen < need);                \
        eq_seen += is_eq_ ? 1 : 0;                                            \
        if (take_) {                                                          \
            float r0_ = (PX) - qx, r1_ = (PY) - qy, r2_ = (PZ) - qz;          \
            s0 += r0_;  s1 += r1_;  s2 += r2_;                                \
            ss0 += r0_ * r0_;  ss1 += r1_ * r1_;  ss2 += r2_ * r2_;           \
            mx0 = fmaxf(mx0, r0_); mx1 = fmaxf(mx1, r1_); mx2 = fmaxf(mx2, r2_); \
            mn0 = fminf(mn0, r0_); mn1 = fminf(mn1, r1_); mn2 = fminf(mn2, r2_); \
        }                                                                     \
    }

#define REGION_STATS(WW, CCW, MCW)                                            \
    {                                                                         \
        const unsigned short* flp = fifo + ((WW) * 64 + l) * FSTRIDE;         \
        const int c = (CCW);                                                  \
        const int grp = ((MCW) + 3) >> 2;                                     \
        if (grp > 0) {                                                        \
            float cx0, cy0, cz0, cx1, cy1, cz1, cx2, cy2, cz2, cx3, cy3, cz3; \
            LOADG(flp, 0, cx0, cy0, cz0, cx1, cy1, cz1, cx2, cy2, cz2, cx3, cy3, cz3); \
            for (int g = 0; g < grp; ++g) {                                   \
                float nx0, ny0, nz0, nx1, ny1, nz1, nx2, ny2, nz2, nx3, ny3, nz3; \
                int gn = (g + 1 < grp) ? (g + 1) : g;                         \
                LOADG(flp, gn, nx0, ny0, nz0, nx1, ny1, nz1, nx2, ny2, nz2, nx3, ny3, nz3); \
                int gi = g * 4;                                               \
                STAT1(cx0, cy0, cz0, gi + 0 < c);                             \
                STAT1(cx1, cy1, cz1, gi + 1 < c);                             \
                STAT1(cx2, cy2, cz2, gi + 2 < c);                             \
                STAT1(cx3, cy3, cz3, gi + 3 < c);                             \
                cx0 = nx0; cy0 = ny0; cz0 = nz0;  cx1 = nx1; cy1 = ny1; cz1 = nz1; \
                cx2 = nx2; cy2 = ny2; cz2 = nz2;  cx3 = nx3; cy3 = ny3; cz3 = nz3; \
            }                                                                 \
        }                                                                     \
    }

    REGION_STATS(0, cc0, mc0);
    REGION_STATS(1, cc1, mc1);
    REGION_STATS(2, cc2, mc2);
    REGION_STATS(3, cc3, mc3);
#undef REGION_STATS
#undef STAT1
#undef LOADG

    const float invk = 1.0f / (float)KNN;
    float mu0 = s0 * invk, mu1 = s1 * invk, mu2 = s2 * invk;
    float ex0 = ss0 * invk, ex1 = ss1 * invk, ex2 = ss2 * invk;
    float st0 = sqrtf(fmaxf(ex0 - mu0 * mu0, 0.f));
    float st1 = sqrtf(fmaxf(ex1 - mu1 * mu1, 0.f));
    float st2 = sqrtf(fmaxf(ex2 - mu2 * mu2, 0.f));
    float nrm = sqrtf(mu0 * mu0 + mu1 * mu1 + mu2 * mu2) + 1e-8f;
    float u0 = mu0 / nrm, u1 = mu1 / nrm, u2 = mu2 / nrm;
    float cr0 = qy * u2 - qz * u1;
    float cr1 = qz * u0 - qx * u2;
    float cr2 = qx * u1 - qy * u0;
    float mq0 = fmaxf(mx0 * mx0, mn0 * mn0);
    float mq1 = fmaxf(mx1 * mx1, mn1 * mn1);
    float mq2 = fmaxf(mx2 * mx2, mn2 * mn2);

    // Per-channel wave max-reduce + one atomic. No f[] array.
#define POOLMAX(VAL, C)                                        \
    {                                                          \
        float v_ = (VAL);                                      \
        _Pragma("unroll")                                      \
        for (int off = 32; off >= 1; off >>= 1)                \
            v_ = fmaxf(v_, __shfl_xor(v_, off, 64));           \
        if (l == 0) atomicMax(pool + b * CH + (C), enc_f32(v_)); \
    }
    POOLMAX(qx, 0);  POOLMAX(qy, 1);  POOLMAX(qz, 2);
    POOLMAX(mu0, 3); POOLMAX(mu1, 4); POOLMAX(mu2, 5);
    POOLMAX(mx0, 6); POOLMAX(mx1, 7); POOLMAX(mx2, 8);
    POOLMAX(mn0, 9); POOLMAX(mn1, 10); POOLMAX(mn2, 11);
    POOLMAX(st0, 12); POOLMAX(st1, 13); POOLMAX(st2, 14);
    POOLMAX(qx - mu0, 15); POOLMAX(qy - mu1, 16); POOLMAX(qz - mu2, 17);
    POOLMAX(u0, 18); POOLMAX(u1, 19); POOLMAX(u2, 20);
    POOLMAX(cr0, 21); POOLMAX(cr1, 22); POOLMAX(cr2, 23);
    POOLMAX(mq0, 24); POOLMAX(mq1, 25); POOLMAX(mq2, 26);
    POOLMAX(ex0, 27); POOLMAX(ex1, 28); POOLMAX(ex2, 29);
#undef POOLMAX
}

__global__ void final_mm_kernel(const unsigned* __restrict__ pool,
                                const float* __restrict__ W,
                                const float* __restrict__ bias,
                                float* __restrict__ out) {
    int t = blockIdx.x * blockDim.x + threadIdx.x;
    if (t >= BATCH * 32) return;
    int bb = t >> 5, e = t & 31;
    float acc = bias[e];
#pragma unroll
    for (int c = 0; c < CH; ++c)
        acc += dec_f32(pool[bb * CH + c]) * W[e * CH + c];
    out[bb * 32 + e] = acc;
}

extern "C" void kernel_launch(void* const* d_in, const int* in_sizes, int n_in,
                              void* d_out, int out_size, void* d_ws, size_t ws_size,
                              hipStream_t stream) {
    const float* x    = (const float*)d_in[0];   // [16, 4096, 3] f32
    const float* W    = (const float*)d_in[1];   // [32, 30] f32
    const float* bias = (const float*)d_in[2];   // [32] f32
    float*       out  = (float*)d_out;           // [16, 32] f32

    unsigned* pool = (unsigned*)d_ws;                          // [16,30] @ offset 0
    float*    tcap = (float*)((char*)d_ws + 2048);             // [16,4096] 256 KB

    hipLaunchKernelGGL(init_pool_kernel, dim3(1), dim3(512), 0, stream, pool);
    hipLaunchKernelGGL(knn_bound_kernel, dim3(BATCH * (NPTS / 64)), dim3(512),
                       0, stream, x, tcap);
    hipLaunchKernelGGL(knn_feat_kernel, dim3(BATCH * (NPTS / 64)), dim3(256),
                       0, stream, x, tcap, pool);
    hipLaunchKernelGGL(final_mm_kernel, dim3(1), dim3(512), 0, stream, pool, W, bias, out);
}

// Round 12
// 271.457 us; speedup vs baseline: 1.0067x; 1.0067x over previous
//
#include <hip/hip_runtime.h>

#pragma clang fp contract(off)

#define BATCH 16
#define NPTS  4096
#define KNN   32
#define CH    30

// Kernel A (bound): 8 waves, chunk 512, top-4 per chunk (union 8*4=32 -> bound)
#define NWA     8
#define CHUNKA  (NPTS / NWA)     // 512
// Kernel B (collect+select): 4 waves, chunk 1024, FIFO of d<=t_cap survivors
#define NWB     4
#define CHUNKB  (NPTS / NWB)     // 1024
#define FD      48               // per-(region,lane) FIFO depth; slot FD = trash
#define FSTRIDE 50               // u16 slots per lane column (>= FD+1)

#define INF_F __builtin_inff()

__device__ __forceinline__ unsigned enc_f32(float f) {
    unsigned u = __float_as_uint(f);
    return (u & 0x80000000u) ? ~u : (u | 0x80000000u);
}
__device__ __forceinline__ float dec_f32(unsigned e) {
    unsigned u = (e & 0x80000000u) ? (e & 0x7FFFFFFFu) : ~e;
    return __uint_as_float(u);
}

__device__ __forceinline__ float med3f(float a, float b, float c) {
#if __has_builtin(__builtin_amdgcn_fmed3f)
    return __builtin_amdgcn_fmed3f(a, b, c);
#else
    float r;
    asm("v_med3_f32 %0, %1, %2, %3" : "=v"(r) : "v"(a), "v"(b), "v"(c));
    return r;
#endif
}

// Difference-form squared distance, fma-fixed: ONE formula in EVERY pass of
// BOTH kernels -> bit-identical d everywhere (contract off).
__device__ __forceinline__ float dist3d(float qx, float qy, float qz,
                                        float px, float py, float pz) {
    float r0 = px - qx, r1 = py - qy, r2 = pz - qz;
    return __builtin_fmaf(r0, r0, __builtin_fmaf(r1, r1, r2 * r2));
}

__global__ void init_pool_kernel(unsigned* __restrict__ pool) {
    int i = blockIdx.x * blockDim.x + threadIdx.x;
    if (i < BATCH * CH) pool[i] = 0u;   // 0 is below every encoded finite float
}

// ---- Kernel A: per-query upper bound t_cap on the 32nd-smallest distance.
// Named-scalar top-4; ~30 VGPR needed, fits the lb(512,8) 64-VGPR bucket.
__launch_bounds__(512, 8)
__global__ void knn_bound_kernel(const float* __restrict__ x,
                                 float* __restrict__ tcap) {
    __shared__ float t8[NWA * 64];                 // 2 KB

    const int b   = blockIdx.x >> 6;
    const int qg  = blockIdx.x & 63;
    const int tid = threadIdx.x;
    const int w   = tid >> 6;                      // wave id = chunk id (0..7)
    const int l   = tid & 63;
    const int q   = qg * 64 + l;
    const float* __restrict__ xb = x + (size_t)b * NPTS * 3;

    const float qx = xb[q * 3 + 0], qy = xb[q * 3 + 1], qz = xb[q * 3 + 2];
    const float4* __restrict__ g4 = (const float4*)xb + (size_t)w * (CHUNKA * 3 / 4);

    float B0 = INF_F, B1 = INF_F, B2 = INF_F, B3 = INF_F;

#define INSERT4(dv)                          \
    {                                        \
        B3 = med3f(B2, B3, (dv));            \
        B2 = med3f(B1, B2, (dv));            \
        B1 = med3f(B0, B1, (dv));            \
        B0 = fminf(B0, (dv));                \
    }

#pragma unroll 2
    for (int m4 = 0; m4 < CHUNKA / 4; ++m4) {
        float4 A = g4[3 * m4], B = g4[3 * m4 + 1], C = g4[3 * m4 + 2];
        float d0 = dist3d(qx, qy, qz, A.x, A.y, A.z);
        float d1 = dist3d(qx, qy, qz, A.w, B.x, B.y);
        float d2 = dist3d(qx, qy, qz, B.z, B.w, C.x);
        float d3 = dist3d(qx, qy, qz, C.y, C.z, C.w);
        INSERT4(d0); INSERT4(d1); INSERT4(d2); INSERT4(d3);
    }
#undef INSERT4

    t8[w * 64 + l] = B3;
    __syncthreads();

    if (w == 0) {
        float t = t8[l];
#pragma unroll
        for (int ww = 1; ww < NWA; ++ww) t = fmaxf(t, t8[ww * 64 + l]);
        tcap[(size_t)b * NPTS + q] = t;
    }
}

// ---- Kernel B: collect survivors (d <= t_cap) then exact top-32 + stats.
// launch_bounds min-waves = 1: removes the allocator's high-occupancy goal so
// the 32-entry list + pipeline stay in VGPRs (the lb(256,4) build spilled at
// VGPR_Count=40 and the 1-wave tail ran ~20x slower than its issue cost).
__launch_bounds__(256, 1)
__global__ void knn_feat_kernel(const float* __restrict__ x,
                                const float* __restrict__ tcap,
                                unsigned* __restrict__ pool) {
    __shared__ unsigned short fifo[NWB * 64 * FSTRIDE];    // 25.0 KB [w][l][slot]
    __shared__ unsigned char  cbs[NWB * 64];               // 256 B

    const int b   = blockIdx.x >> 6;
    const int qg  = blockIdx.x & 63;
    const int tid = threadIdx.x;
    const int w   = tid >> 6;                      // wave id = chunk id (0..3)
    const int l   = tid & 63;
    const int q   = qg * 64 + l;
    const float* __restrict__ xb = x + (size_t)b * NPTS * 3;

    const float qx = xb[q * 3 + 0], qy = xb[q * 3 + 1], qz = xb[q * 3 + 2];
    const float t_cap = tcap[(size_t)b * NPTS + q];

    const float4* __restrict__ g4 = (const float4*)xb + (size_t)w * (CHUNKB * 3 / 4);

    // Pass 2: branchless collect of GLOBAL u16 indices with d <= t_cap.
    unsigned short* __restrict__ fl = fifo + (w * 64 + l) * FSTRIDE;
    int cnt = 0;
#pragma unroll 2
    for (int m4 = 0; m4 < CHUNKB / 4; ++m4) {
        float4 A = g4[3 * m4], B = g4[3 * m4 + 1], C = g4[3 * m4 + 2];
        float d0 = dist3d(qx, qy, qz, A.x, A.y, A.z);
        float d1 = dist3d(qx, qy, qz, A.w, B.x, B.y);
        float d2 = dist3d(qx, qy, qz, B.z, B.w, C.x);
        float d3 = dist3d(qx, qy, qz, C.y, C.z, C.w);
        int mb = w * CHUNKB + m4 * 4;              // global candidate index
        { bool t = (d0 <= t_cap) && (cnt < FD); fl[t ? cnt : FD] = (unsigned short)(mb + 0); cnt += t; }
        { bool t = (d1 <= t_cap) && (cnt < FD); fl[t ? cnt : FD] = (unsigned short)(mb + 1); cnt += t; }
        { bool t = (d2 <= t_cap) && (cnt < FD); fl[t ? cnt : FD] = (unsigned short)(mb + 2); cnt += t; }
        { bool t = (d3 <= t_cap) && (cnt < FD); fl[t ? cnt : FD] = (unsigned short)(mb + 3); cnt += t; }
    }
    cbs[w * 64 + l] = (unsigned char)cnt;
    __syncthreads();

    if (w != 0) return;   // no barriers past this point

    // ---- Phase 3 (wave 0): named-scalar top-32 + stats, pipelined loads. ----
    int cc0 = cbs[0 * 64 + l], cc1 = cbs[1 * 64 + l],
        cc2 = cbs[2 * 64 + l], cc3 = cbs[3 * 64 + l];

#define WMAX(v_)                                          \
    {                                                     \
        _Pragma("unroll")                                 \
        for (int off = 32; off >= 1; off >>= 1) {         \
            int o_ = __shfl_xor((v_), off, 64);           \
            (v_) = (o_ > (v_)) ? o_ : (v_);               \
        }                                                 \
    }
    int mc0 = cc0; WMAX(mc0);
    int mc1 = cc1; WMAX(mc1);
    int mc2 = cc2; WMAX(mc2);
    int mc3 = cc3; WMAX(mc3);
#undef WMAX

    // Named top-32 list (ascending). Descending insert reads old neighbors.
    float A00 = INF_F, A01 = INF_F, A02 = INF_F, A03 = INF_F,
          A04 = INF_F, A05 = INF_F, A06 = INF_F, A07 = INF_F,
          A08 = INF_F, A09 = INF_F, A10 = INF_F, A11 = INF_F,
          A12 = INF_F, A13 = INF_F, A14 = INF_F, A15 = INF_F,
          A16 = INF_F, A17 = INF_F, A18 = INF_F, A19 = INF_F,
          A20 = INF_F, A21 = INF_F, A22 = INF_F, A23 = INF_F,
          A24 = INF_F, A25 = INF_F, A26 = INF_F, A27 = INF_F,
          A28 = INF_F, A29 = INF_F, A30 = INF_F, A31 = INF_F;

#define INS32(D)                                                              \
    {                                                                         \
        A31 = med3f(A30, A31, (D)); A30 = med3f(A29, A30, (D));               \
        A29 = med3f(A28, A29, (D)); A28 = med3f(A27, A28, (D));               \
        A27 = med3f(A26, A27, (D)); A26 = med3f(A25, A26, (D));               \
        A25 = med3f(A24, A25, (D)); A24 = med3f(A23, A24, (D));               \
        A23 = med3f(A22, A23, (D)); A22 = med3f(A21, A22, (D));               \
        A21 = med3f(A20, A21, (D)); A20 = med3f(A19, A20, (D));               \
        A19 = med3f(A18, A19, (D)); A18 = med3f(A17, A18, (D));               \
        A17 = med3f(A16, A17, (D)); A16 = med3f(A15, A16, (D));               \
        A15 = med3f(A14, A15, (D)); A14 = med3f(A13, A14, (D));               \
        A13 = med3f(A12, A13, (D)); A12 = med3f(A11, A12, (D));               \
        A11 = med3f(A10, A11, (D)); A10 = med3f(A09, A10, (D));               \
        A09 = med3f(A08, A09, (D)); A08 = med3f(A07, A08, (D));               \
        A07 = med3f(A06, A07, (D)); A06 = med3f(A05, A06, (D));               \
        A05 = med3f(A04, A05, (D)); A04 = med3f(A03, A04, (D));               \
        A03 = med3f(A02, A03, (D)); A02 = med3f(A01, A02, (D));               \
        A01 = med3f(A00, A01, (D)); A00 = fminf(A00, (D));                    \
    }

    // Load 4 survivor coords for group g_ (garbage slots masked in-bounds).
#define LOADG(flp, g_, X0, Y0, Z0, X1, Y1, Z1, X2, Y2, Z2, X3, Y3, Z3)        \
    {                                                                         \
        const unsigned* p32_ = (const unsigned*)((flp) + (g_) * 4);           \
        unsigned v0_ = p32_[0], v1_ = p32_[1];                                \
        int i0_ = (int)(v0_ & 0xFFFu);                                        \
        int i1_ = (int)((v0_ >> 16) & 0xFFFu);                                \
        int i2_ = (int)(v1_ & 0xFFFu);                                        \
        int i3_ = (int)((v1_ >> 16) & 0xFFFu);                                \
        const float* p0_ = xb + 3 * i0_;                                      \
        const float* p1_ = xb + 3 * i1_;                                      \
        const float* p2_ = xb + 3 * i2_;                                      \
        const float* p3_ = xb + 3 * i3_;                                      \
        X0 = p0_[0]; Y0 = p0_[1]; Z0 = p0_[2];                                \
        X1 = p1_[0]; Y1 = p1_[1]; Z1 = p1_[2];                                \
        X2 = p2_[0]; Y2 = p2_[1]; Z2 = p2_[2];                                \
        X3 = p3_[0]; Y3 = p3_[1]; Z3 = p3_[2];                                \
    }

#define REGION_SELECT(WW, CCW, MCW)                                           \
    {                                                                         \
        const unsigned short* flp = fifo + ((WW) * 64 + l) * FSTRIDE;         \
        const int c = (CCW);                                                  \
        const int grp = ((MCW) + 3) >> 2;                                     \
        if (grp > 0) {                                                        \
            float cx0, cy0, cz0, cx1, cy1, cz1, cx2, cy2, cz2, cx3, cy3, cz3; \
            LOADG(flp, 0, cx0, cy0, cz0, cx1, cy1, cz1, cx2, cy2, cz2, cx3, cy3, cz3); \
            for (int g = 0; g < grp; ++g) {                                   \
                float nx0, ny0, nz0, nx1, ny1, nz1, nx2, ny2, nz2, nx3, ny3, nz3; \
                int gn = (g + 1 < grp) ? (g + 1) : g;                         \
                LOADG(flp, gn, nx0, ny0, nz0, nx1, ny1, nz1, nx2, ny2, nz2, nx3, ny3, nz3); \
                float d0 = dist3d(qx, qy, qz, cx0, cy0, cz0);                 \
                float d1 = dist3d(qx, qy, qz, cx1, cy1, cz1);                 \
                float d2 = dist3d(qx, qy, qz, cx2, cy2, cz2);                 \
                float d3 = dist3d(qx, qy, qz, cx3, cy3, cz3);                 \
                int gi = g * 4;                                               \
                d0 = (gi + 0 < c) ? d0 : INF_F;                               \
                d1 = (gi + 1 < c) ? d1 : INF_F;                               \
                d2 = (gi + 2 < c) ? d2 : INF_F;                               \
                d3 = (gi + 3 < c) ? d3 : INF_F;                               \
                INS32(d0); INS32(d1); INS32(d2); INS32(d3);                   \
                cx0 = nx0; cy0 = ny0; cz0 = nz0;  cx1 = nx1; cy1 = ny1; cz1 = nz1; \
                cx2 = nx2; cy2 = ny2; cz2 = nz2;  cx3 = nx3; cy3 = ny3; cz3 = nz3; \
            }                                                                 \
        }                                                                     \
    }

    REGION_SELECT(0, cc0, mc0);
    REGION_SELECT(1, cc1, mc1);
    REGION_SELECT(2, cc2, mc2);
    REGION_SELECT(3, cc3, mc3);
#undef REGION_SELECT
#undef INS32

    const float thr = A31;
    int c_lt = (A00 < thr) + (A01 < thr) + (A02 < thr) + (A03 < thr)
             + (A04 < thr) + (A05 < thr) + (A06 < thr) + (A07 < thr)
             + (A08 < thr) + (A09 < thr) + (A10 < thr) + (A11 < thr)
             + (A12 < thr) + (A13 < thr) + (A14 < thr) + (A15 < thr)
             + (A16 < thr) + (A17 < thr) + (A18 < thr) + (A19 < thr)
             + (A20 < thr) + (A21 < thr) + (A22 < thr) + (A23 < thr)
             + (A24 < thr) + (A25 < thr) + (A26 < thr) + (A27 < thr)
             + (A28 < thr) + (A29 < thr) + (A30 < thr) + (A31 < thr);
    const int need = KNN - c_lt;                   // ties to take, in index order

    // ---- Stats pass over the same survivors (same pipeline). ----
    float s0 = 0.f, s1 = 0.f, s2 = 0.f;
    float ss0 = 0.f, ss1 = 0.f, ss2 = 0.f;
    float mx0 = -INF_F, mx1 = -INF_F, mx2 = -INF_F;
    float mn0 =  INF_F, mn1 =  INF_F, mn2 =  INF_F;
    int eq_seen = 0;

#define STAT1(PX, PY, PZ, ACT)                                                \
    {                                                                         \
        float d_ = dist3d(qx, qy, qz, (PX), (PY), (PZ));                      \
        d_ = (ACT) ? d_ : INF_F;                                              \
        bool is_eq_ = (d_ == thr);                                            \
        bool take_ = (d_ < thr) || (is_eq_ && eq_seen < need);                \
        eq_seen += is_eq_ ? 1 : 0;                                            \
        if (take_) {                                                          \
            float r0_ = (PX) - qx, r1_ = (PY) - qy, r2_ = (PZ) - qz;          \
            s0 += r0_;  s1 += r1_;  s2 += r2_;                                \
            ss0 += r0_ * r0_;  ss1 += r1_ * r1_;  ss2 += r2_ * r2_;           \
            mx0 = fmaxf(mx0, r0_); mx1 = fmaxf(mx1, r1_); mx2 = fmaxf(mx2, r2_); \
            mn0 = fminf(mn0, r0_); mn1 = fminf(mn1, r1_); mn2 = fminf(mn2, r2_); \
        }                                                                     \
    }

#define REGION_STATS(WW, CCW, MCW)                                            \
    {                                                                         \
        const unsigned short* flp = fifo + ((WW) * 64 + l) * FSTRIDE;         \
        const int c = (CCW);                                                  \
        const int grp = ((MCW) + 3) >> 2;                                     \
        if (grp > 0) {                                                        \
            float cx0, cy0, cz0, cx1, cy1, cz1, cx2, cy2, cz2, cx3, cy3, cz3; \
            LOADG(flp, 0, cx0, cy0, cz0, cx1, cy1, cz1, cx2, cy2, cz2, cx3, cy3, cz3); \
            for (int g = 0; g < grp; ++g) {                                   \
                float nx0, ny0, nz0, nx1, ny1, nz1, nx2, ny2, nz2, nx3, ny3, nz3; \
                int gn = (g + 1 < grp) ? (g + 1) : g;                         \
                LOADG(flp, gn, nx0, ny0, nz0, nx1, ny1, nz1, nx2, ny2, nz2, nx3, ny3, nz3); \
                int gi = g * 4;                                               \
                STAT1(cx0, cy0, cz0, gi + 0 < c);                             \
                STAT1(cx1, cy1, cz1, gi + 1 < c);                             \
                STAT1(cx2, cy2, cz2, gi + 2 < c);                             \
                STAT1(cx3, cy3, cz3, gi + 3 < c);                             \
                cx0 = nx0; cy0 = ny0; cz0 = nz0;  cx1 = nx1; cy1 = ny1; cz1 = nz1; \
                cx2 = nx2; cy2 = ny2; cz2 = nz2;  cx3 = nx3; cy3 = ny3; cz3 = nz3; \
            }                                                                 \
        }                                                                     \
    }

    REGION_STATS(0, cc0, mc0);
    REGION_STATS(1, cc1, mc1);
    REGION_STATS(2, cc2, mc2);
    REGION_STATS(3, cc3, mc3);
#undef REGION_STATS
#undef STAT1
#undef LOADG

    const float invk = 1.0f / (float)KNN;
    float mu0 = s0 * invk, mu1 = s1 * invk, mu2 = s2 * invk;
    float ex0 = ss0 * invk, ex1 = ss1 * invk, ex2 = ss2 * invk;
    float st0 = sqrtf(fmaxf(ex0 - mu0 * mu0, 0.f));
    float st1 = sqrtf(fmaxf(ex1 - mu1 * mu1, 0.f));
    float st2 = sqrtf(fmaxf(ex2 - mu2 * mu2, 0.f));
    float nrm = sqrtf(mu0 * mu0 + mu1 * mu1 + mu2 * mu2) + 1e-8f;
    float u0 = mu0 / nrm, u1 = mu1 / nrm, u2 = mu2 / nrm;
    float cr0 = qy * u2 - qz * u1;
    float cr1 = qz * u0 - qx * u2;
    float cr2 = qx * u1 - qy * u0;
    float mq0 = fmaxf(mx0 * mx0, mn0 * mn0);
    float mq1 = fmaxf(mx1 * mx1, mn1 * mn1);
    float mq2 = fmaxf(mx2 * mx2, mn2 * mn2);

    // Per-channel wave max-reduce + one atomic. No f[] array.
#define POOLMAX(VAL, C)                                        \
    {                                                          \
        float v_ = (VAL);                                      \
        _Pragma("unroll")                                      \
        for (int off = 32; off >= 1; off >>= 1)                \
            v_ = fmaxf(v_, __shfl_xor(v_, off, 64));           \
        if (l == 0) atomicMax(pool + b * CH + (C), enc_f32(v_)); \
    }
    POOLMAX(qx, 0);  POOLMAX(qy, 1);  POOLMAX(qz, 2);
    POOLMAX(mu0, 3); POOLMAX(mu1, 4); POOLMAX(mu2, 5);
    POOLMAX(mx0, 6); POOLMAX(mx1, 7); POOLMAX(mx2, 8);
    POOLMAX(mn0, 9); POOLMAX(mn1, 10); POOLMAX(mn2, 11);
    POOLMAX(st0, 12); POOLMAX(st1, 13); POOLMAX(st2, 14);
    POOLMAX(qx - mu0, 15); POOLMAX(qy - mu1, 16); POOLMAX(qz - mu2, 17);
    POOLMAX(u0, 18); POOLMAX(u1, 19); POOLMAX(u2, 20);
    POOLMAX(cr0, 21); POOLMAX(cr1, 22); POOLMAX(cr2, 23);
    POOLMAX(mq0, 24); POOLMAX(mq1, 25); POOLMAX(mq2, 26);
    POOLMAX(ex0, 27); POOLMAX(ex1, 28); POOLMAX(ex2, 29);
#undef POOLMAX
}

__global__ void final_mm_kernel(const unsigned* __restrict__ pool,
                                const float* __restrict__ W,
                                const float* __restrict__ bias,
                                float* __restrict__ out) {
    int t = blockIdx.x * blockDim.x + threadIdx.x;
    if (t >= BATCH * 32) return;
    int bb = t >> 5, e = t & 31;
    float acc = bias[e];
#pragma unroll
    for (int c = 0; c < CH; ++c)
        acc += dec_f32(pool[bb * CH + c]) * W[e * CH + c];
    out[bb * 32 + e] = acc;
}

extern "C" void kernel_launch(void* const* d_in, const int* in_sizes, int n_in,
                              void* d_out, int out_size, void* d_ws, size_t ws_size,
                              hipStream_t stream) {
    const float* x    = (const float*)d_in[0];   // [16, 4096, 3] f32
    const float* W    = (const float*)d_in[1];   // [32, 30] f32
    const float* bias = (const float*)d_in[2];   // [32] f32
    float*       out  = (float*)d_out;           // [16, 32] f32

    unsigned* pool = (unsigned*)d_ws;                          // [16,30] @ offset 0
    float*    tcap = (float*)((char*)d_ws + 2048);             // [16,4096] 256 KB

    hipLaunchKernelGGL(init_pool_kernel, dim3(1), dim3(512), 0, stream, pool);
    hipLaunchKernelGGL(knn_bound_kernel, dim3(BATCH * (NPTS / 64)), dim3(512),
                       0, stream, x, tcap);
    hipLaunchKernelGGL(knn_feat_kernel, dim3(BATCH * (NPTS / 64)), dim3(256),
                       0, stream, x, tcap, pool);
    hipLaunchKernelGGL(final_mm_kernel, dim3(1), dim3(512), 0, stream, pool, W, bias, out);
}